// Round 8
// baseline (429.425 us; speedup 1.0000x reference)
//
#include <hip/hip_runtime.h>
#include <math.h>

// ---------------------------------------------------------------------------
// Round 17: occupancy-driven overlap.  R16 counters: MfmaUtil 23.5% (=20.4us,
// exactly the Dekker MFMA floor -> matrix pipe accounted), VALUBusy 42%
// (=36.5us, largest pipe), occupancy 18.6% (80KB LDS -> 2 blocks/CU); ~35%
// of cycles neither pipe = barrier/dep-chain gaps with too few waves to fill.
// Change: KVBLK 64 -> 32 halves LDS to 40KB -> 4 blocks/CU (16 waves), 64
// finer tiles, same pipeline skeleton/swizzles/XCD-remap.  Online-softmax
// cadence changes (64x32 vs 32x64) - same math, f32 rounding shifts only;
// R10/R13 evidence says absmax stays 54.0-class.
// Predicted: occ 18.6 -> ~34%, attn 87 -> ~62-70us, total 405 -> ~360us.
// ---------------------------------------------------------------------------

typedef _Float16 f16x8 __attribute__((ext_vector_type(8)));
typedef _Float16 f16x2 __attribute__((ext_vector_type(2)));
typedef float f32x4 __attribute__((ext_vector_type(4)));
#define MFMA16(a, b, c) __builtin_amdgcn_mfma_f32_16x16x32_f16((a), (b), (c), 0, 0, 0)

// ---------------------------------------------------------------------------
// Kernel 1: per-token abs-max scale (f64 decisions).  UNCHANGED (green).
// ---------------------------------------------------------------------------
__global__ __launch_bounds__(256) void token_scale(
    const float* __restrict__ x0, const float* __restrict__ x1,
    const float* __restrict__ x2, double* __restrict__ out)
{
    const int t = blockIdx.x;
    const int z = blockIdx.y;
    const float* __restrict__ x = (z == 0) ? x0 : ((z == 1) ? x1 : x2);
    const int tid = threadIdx.x;
    float m = 0.0f;
#pragma unroll
    for (int i = 0; i < 2; ++i) {
        int f = i * 256 + tid;
        int b = f >> 7, d4 = f & 127;
        float4 v = *(const float4*)(x + (long)(b * 2048 + t) * 512 + d4 * 4);
        m = fmaxf(m, fmaxf(fmaxf(fabsf(v.x), fabsf(v.y)), fmaxf(fabsf(v.z), fabsf(v.w))));
    }
#pragma unroll
    for (int off = 1; off < 64; off <<= 1) m = fmaxf(m, __shfl_xor(m, off));
    __shared__ float red[4];
    if ((tid & 63) == 0) red[tid >> 6] = m;
    __syncthreads();
    if (tid == 0) {
        m = fmaxf(fmaxf(red[0], red[1]), fmaxf(red[2], red[3]));
        out[z * 2048 + t] = fmax((double)m / 127.0, 1e-8);
    }
}

// ---------------------------------------------------------------------------
// Kernel 2: weight quantization.  UNCHANGED (green R11).
// ---------------------------------------------------------------------------
__global__ __launch_bounds__(256) void wquant(
    const float* __restrict__ Wq, const float* __restrict__ Wk,
    const float* __restrict__ Wv, double* __restrict__ sw,
    _Float16* __restrict__ qW)
{
    const int z = blockIdx.y;
    const float* __restrict__ W = (z == 0) ? Wq : (z == 1) ? Wk : Wv;
    const int col0 = blockIdx.x * 64;
    const int tid = threadIdx.x;
    const int c = tid & 63, kg = tid >> 6;

    __shared__ float redm[4][64];
    __shared__ double sS[64];
    __shared__ __align__(16) _Float16 qs[64][520];

    float m = 0.0f;
    for (int k = kg; k < 512; k += 4)
        m = fmaxf(m, fabsf(W[k * 512 + col0 + c]));
    redm[kg][c] = m;
    __syncthreads();
    if (tid < 64) {
        float mm = fmaxf(fmaxf(redm[0][tid], redm[1][tid]),
                         fmaxf(redm[2][tid], redm[3][tid]));
        double s = fmax((double)mm / 127.0, 1e-8);
        sw[z * 512 + col0 + tid] = s;
        sS[tid] = s;
    }
    __syncthreads();

    const double s = sS[c];
    for (int k = kg; k < 512; k += 4)
        qs[c][k] = (_Float16)fmin(fmax(rint((double)W[k * 512 + col0 + c] / s), -128.0), 127.0);
    __syncthreads();

    const int wc = tid >> 2, kc = (tid & 3) * 128;
    _Float16* q = qW + (long)z * 262144 + (long)(col0 + wc) * 512 + kc;
#pragma unroll
    for (int j = 0; j < 16; ++j)
        *(f16x8*)(q + j * 8) = *(const f16x8*)(&qs[wc][kc + j * 8]);
}

// ---------------------------------------------------------------------------
// Kernel 2b: activation quantization into f16 int planes.  UNCHANGED (R12).
// ---------------------------------------------------------------------------
__global__ __launch_bounds__(256) void aquant(
    const float* __restrict__ x0, const float* __restrict__ x1,
    const float* __restrict__ x2, const double* __restrict__ sAll,
    _Float16* __restrict__ qA)
{
    const int z = blockIdx.y;
    const float* __restrict__ x = (z == 0) ? x0 : ((z == 1) ? x1 : x2);
    const double* __restrict__ s = sAll + z * 2048;
    const long PLANE = (long)4 * 2048 * 512;
    const long f = ((long)blockIdx.x * 256 + threadIdx.x) * 8;
    float4 v0 = *(const float4*)(x + f);
    float4 v1 = *(const float4*)(x + f + 4);
    const double sc = s[(f >> 9) & 2047];
    f16x8 q;
    q[0] = (_Float16)fmin(fmax(rint((double)v0.x / sc), -128.0), 127.0);
    q[1] = (_Float16)fmin(fmax(rint((double)v0.y / sc), -128.0), 127.0);
    q[2] = (_Float16)fmin(fmax(rint((double)v0.z / sc), -128.0), 127.0);
    q[3] = (_Float16)fmin(fmax(rint((double)v0.w / sc), -128.0), 127.0);
    q[4] = (_Float16)fmin(fmax(rint((double)v1.x / sc), -128.0), 127.0);
    q[5] = (_Float16)fmin(fmax(rint((double)v1.y / sc), -128.0), 127.0);
    q[6] = (_Float16)fmin(fmax(rint((double)v1.z / sc), -128.0), 127.0);
    q[7] = (_Float16)fmin(fmax(rint((double)v1.w / sc), -128.0), 127.0);
    *(f16x8*)(qA + (long)z * PLANE + f) = q;
}

// ---------------------------------------------------------------------------
// Kernel 2c: one-shot Wf transpose + Dekker hi/lo split.  UNCHANGED (R12).
// ---------------------------------------------------------------------------
__global__ __launch_bounds__(256) void wfsplit(
    const float* __restrict__ Wf, _Float16* __restrict__ WhT,
    _Float16* __restrict__ WlT)
{
    const int n0 = blockIdx.x * 64, k0 = blockIdx.y * 64;
    const int tid = threadIdx.x;
    __shared__ float T[64 * 68];
    {
        const int kr = tid >> 2, nc = (tid & 3) * 16;
#pragma unroll
        for (int j = 0; j < 4; ++j) {
            float4 v = *(const float4*)(Wf + (long)(k0 + kr) * 512 + n0 + nc + 4 * j);
            T[kr * 68 + nc + 4 * j + 0] = v.x;
            T[kr * 68 + nc + 4 * j + 1] = v.y;
            T[kr * 68 + nc + 4 * j + 2] = v.z;
            T[kr * 68 + nc + 4 * j + 3] = v.w;
        }
    }
    __syncthreads();
    const int nr = tid >> 2, kc = (tid & 3) * 16;
    f16x8 h[2], l[2];
#pragma unroll
    for (int j = 0; j < 16; ++j) {
        float wv = T[(kc + j) * 68 + nr];
        _Float16 hi = (_Float16)wv;
        h[j >> 3][j & 7] = hi;
        l[j >> 3][j & 7] = (_Float16)(wv - (float)hi);
    }
    *(f16x8*)(WhT + (long)(n0 + nr) * 512 + k0 + kc) = h[0];
    *(f16x8*)(WhT + (long)(n0 + nr) * 512 + k0 + kc + 8) = h[1];
    *(f16x8*)(WlT + (long)(n0 + nr) * 512 + k0 + kc) = l[0];
    *(f16x8*)(WlT + (long)(n0 + nr) * 512 + k0 + kc + 8) = l[1];
}

// ---------------------------------------------------------------------------
// Kernel 3: projection GEMM on the f16 MFMA pipe.  UNCHANGED (green R12).
// ---------------------------------------------------------------------------
__global__ __launch_bounds__(256) void proj_mfma(
    const _Float16* __restrict__ qA, const _Float16* __restrict__ qW,
    const double* __restrict__ saAll, const double* __restrict__ swAll,
    _Float16* __restrict__ Qh, _Float16* __restrict__ Ql,
    _Float16* __restrict__ Kh, _Float16* __restrict__ Kl,
    _Float16* __restrict__ Vh, _Float16* __restrict__ Vl,
    int b)
{
    const int z = blockIdx.z;
    const _Float16* __restrict__ A = qA + ((long)z * 4 + b) * (2048l * 512);
    const _Float16* __restrict__ Bq = qW + (long)z * 262144;
    const double* __restrict__ sa = saAll + z * 2048;
    const double* __restrict__ swz = swAll + z * 512;

    const int m0 = blockIdx.x * 64, n0 = blockIdx.y * 64;
    const int tid = threadIdx.x;
    const int w = tid >> 6, lane = tid & 63;
    const int ln = lane & 15, quad = lane >> 4;

    __shared__ __align__(16) _Float16 As[64 * 72];
    __shared__ __align__(16) _Float16 Bs[64 * 72];
    const int srow = tid >> 3, scs = (tid & 7) * 8;

    f32x4 c[4];
#pragma unroll
    for (int nt = 0; nt < 4; ++nt) { c[nt][0] = 0; c[nt][1] = 0; c[nt][2] = 0; c[nt][3] = 0; }

    f16x8 a0, a1, b0, b1;
    a0 = *(const f16x8*)(A + (long)(m0 + srow) * 512 + scs);
    a1 = *(const f16x8*)(A + (long)(m0 + 32 + srow) * 512 + scs);
    b0 = *(const f16x8*)(Bq + (long)(n0 + srow) * 512 + scs);
    b1 = *(const f16x8*)(Bq + (long)(n0 + 32 + srow) * 512 + scs);

    for (int k0 = 0; k0 < 512; k0 += 64) {
        __syncthreads();
        *(f16x8*)(As + srow * 72 + scs) = a0;
        *(f16x8*)(As + (32 + srow) * 72 + scs) = a1;
        *(f16x8*)(Bs + srow * 72 + scs) = b0;
        *(f16x8*)(Bs + (32 + srow) * 72 + scs) = b1;
        __syncthreads();
        if (k0 + 64 < 512) {
            a0 = *(const f16x8*)(A + (long)(m0 + srow) * 512 + k0 + 64 + scs);
            a1 = *(const f16x8*)(A + (long)(m0 + 32 + srow) * 512 + k0 + 64 + scs);
            b0 = *(const f16x8*)(Bq + (long)(n0 + srow) * 512 + k0 + 64 + scs);
            b1 = *(const f16x8*)(Bq + (long)(n0 + 32 + srow) * 512 + k0 + 64 + scs);
        }
#pragma unroll
        for (int ks = 0; ks < 2; ++ks) {
            f16x8 aF = *(const f16x8*)(As + (w * 16 + ln) * 72 + ks * 32 + quad * 8);
#pragma unroll
            for (int nt = 0; nt < 4; ++nt) {
                f16x8 bF = *(const f16x8*)(Bs + (nt * 16 + ln) * 72 + ks * 32 + quad * 8);
                c[nt] = MFMA16(aF, bF, c[nt]);
            }
        }
    }

#pragma unroll
    for (int nt = 0; nt < 4; ++nt)
#pragma unroll
        for (int r = 0; r < 4; ++r) {
            int t = m0 + w * 16 + quad * 4 + r;
            int n = n0 + nt * 16 + ln;
            float val = (float)((double)c[nt][r] * sa[t] * swz[n]);
            _Float16 hi = (_Float16)val;
            _Float16 lo = (_Float16)(val - (float)hi);
            int hh = n >> 6, d = n & 63;
            if (z == 2) {
                long idx = ((long)hh * 64 + d) * 2048 + t;     // transposed
                Vh[idx] = hi; Vl[idx] = lo;
            } else if (z == 1) {
                long idx = ((long)hh * 2048 + t) * 64 + d;
                Kh[idx] = hi; Kl[idx] = lo;
            } else {
                long idx = ((long)hh * 2048 + t) * 64 + d;
                Qh[idx] = hi; Ql[idx] = lo;
            }
        }
}

// ---------------------------------------------------------------------------
// Kernel 4: attention, pipelined, KVBLK=32 (this round).  4 waves / 64 q.
// 40 KB LDS -> 4 blocks/CU.  Same pipeline skeleton/swizzles as R16.
// ---------------------------------------------------------------------------
__global__ __launch_bounds__(256) void attn_mfma(
    const _Float16* __restrict__ Qh0, const _Float16* __restrict__ Ql0,
    const _Float16* __restrict__ Kh0, const _Float16* __restrict__ Kl0,
    const _Float16* __restrict__ Vh0, const _Float16* __restrict__ Vl0,
    float* __restrict__ xbuf, int bbase)
{
    // ---- XCD-aware bijective remap (R14): XCD x owns head x, both slots ----
    const int wg = blockIdx.x + (blockIdx.y << 5) + (blockIdx.z << 8);
    const int xcd = wg & 7, j = wg >> 3;
    const int pair = (xcd << 1) + (j >> 5);
    const int q0 = (j & 31) * 64;
    const int h = pair >> 1;
    const int slot = pair & 1;
    const int b = bbase + slot;

    const long PE = (long)8 * 2048 * 64;
    const _Float16* __restrict__ Qh = Qh0 + (long)slot * PE;
    const _Float16* __restrict__ Ql = Ql0 + (long)slot * PE;
    const _Float16* __restrict__ Kh = Kh0 + (long)slot * PE;
    const _Float16* __restrict__ Kl = Kl0 + (long)slot * PE;
    const _Float16* __restrict__ Vh = Vh0 + (long)slot * PE;
    const _Float16* __restrict__ Vl = Vl0 + (long)slot * PE;

    const int tid = threadIdx.x;
    const int w = tid >> 6, lane = tid & 63;
    const int ln = lane & 15, quad = lane >> 4;
    const int swz8 = ln & 7, swz4 = ln & 3;

    // double-buffered swizzled tiles (KVBLK=32): 40 KB total
    __shared__ __align__(16) _Float16 KsH[2][2048];   // [buf][32 keys x 64 d]
    __shared__ __align__(16) _Float16 KsL[2][2048];
    __shared__ __align__(16) _Float16 VsH[2][2048];   // [buf][64 d x 32 keys]
    __shared__ __align__(16) _Float16 VsL[2][2048];
    __shared__ __align__(16) _Float16 PTh[4][512];    // [wave][16 q x 32 keys]
    __shared__ __align__(16) _Float16 PTl[4][512];

    // Q fragment registers (same content serves as Q^T B-operand)
    f16x8 qh[2], ql[2];
    {
        const long r = ((long)h * 2048 + q0 + w * 16 + ln) * 64 + quad * 8;
        qh[0] = *(const f16x8*)(Qh + r);
        qh[1] = *(const f16x8*)(Qh + r + 32);
        ql[0] = *(const f16x8*)(Ql + r);
        ql[1] = *(const f16x8*)(Ql + r + 32);
    }

    float m_run = -INFINITY, l_run = 0.0f;
    f32x4 O[4];
#pragma unroll
    for (int dt = 0; dt < 4; ++dt) { O[dt][0] = 0; O[dt][1] = 0; O[dt][2] = 0; O[dt][3] = 0; }

    // staging: K 32 rows x 8 chunks; V^T 64 rows x 4 chunks (1 f16x8 each)
    const int kRow = tid >> 3, kCh = tid & 7;
    const int kSl  = kRow * 64 + ((kCh ^ (kRow & 7)) << 3);
    const int vRow = tid >> 2, vCh = tid & 3;
    const int vSl  = vRow * 32 + ((vCh ^ (vRow & 3)) << 3);
    const long kBase = (long)h * 2048;
    const long vBase = (long)h * 64;
    f16x8 sgKh, sgKl, sgVh, sgVl;

    auto LOADT = [&](int kt) {
        sgKh = *(const f16x8*)(Kh + (kBase + kt + kRow) * 64 + kCh * 8);
        sgKl = *(const f16x8*)(Kl + (kBase + kt + kRow) * 64 + kCh * 8);
        sgVh = *(const f16x8*)(Vh + (vBase + vRow) * 2048 + kt + vCh * 8);
        sgVl = *(const f16x8*)(Vl + (vBase + vRow) * 2048 + kt + vCh * 8);
    };
    auto STORET = [&](int bs) {
        *(f16x8*)(&KsH[bs][kSl]) = sgKh;
        *(f16x8*)(&KsL[bs][kSl]) = sgKl;
        *(f16x8*)(&VsH[bs][vSl]) = sgVh;
        *(f16x8*)(&VsL[bs][vSl]) = sgVl;
    };
    auto STEP_S = [&](int bs, f32x4* sT) {
        __builtin_amdgcn_s_setprio(1);
#pragma unroll
        for (int kt = 0; kt < 2; ++kt) {
            f32x4 s; s[0] = 0; s[1] = 0; s[2] = 0; s[3] = 0;
#pragma unroll
            for (int ks = 0; ks < 2; ++ks) {
                const int off = (kt * 16 + ln) * 64 + (((ks * 4 + quad) ^ swz8) << 3);
                f16x8 kh = *(const f16x8*)(&KsH[bs][off]);
                f16x8 kl = *(const f16x8*)(&KsL[bs][off]);
                s = MFMA16(kl, qh[ks], s);
                s = MFMA16(kh, ql[ks], s);
                s = MFMA16(kh, qh[ks], s);
            }
            sT[kt] = s;
        }
        __builtin_amdgcn_s_setprio(0);
    };
    auto STEP_PV = [&](int bs) {
        __builtin_amdgcn_s_setprio(1);
        const int pc = (quad ^ swz4) << 3;
        f16x8 ph = *(const f16x8*)(&PTh[w][ln * 32 + pc]);
        f16x8 pl = *(const f16x8*)(&PTl[w][ln * 32 + pc]);
#pragma unroll
        for (int dt = 0; dt < 4; ++dt) {
            const int off = (dt * 16 + ln) * 32 + pc;
            f16x8 vh = *(const f16x8*)(&VsH[bs][off]);
            f16x8 vl = *(const f16x8*)(&VsL[bs][off]);
            O[dt] = MFMA16(vh, pl, O[dt]);
            O[dt] = MFMA16(vl, ph, O[dt]);
            O[dt] = MFMA16(vh, ph, O[dt]);
        }
        __builtin_amdgcn_s_setprio(0);
    };
    auto STEP_SM = [&](f32x4* sT) {
        float rm = -INFINITY;
#pragma unroll
        for (int kt = 0; kt < 2; ++kt)
#pragma unroll
            for (int r = 0; r < 4; ++r) rm = fmaxf(rm, sT[kt][r]);
        rm = fmaxf(rm, __shfl_xor(rm, 16));
        rm = fmaxf(rm, __shfl_xor(rm, 32));
        const float mn = fmaxf(m_run, rm);
        const float a = __expf((m_run - mn) * 0.125f);
        m_run = mn;
        float sum = 0.0f;
#pragma unroll
        for (int kt = 0; kt < 2; ++kt) {
#pragma unroll
            for (int r = 0; r < 4; r += 2) {
                float p0 = __expf((sT[kt][r]     - mn) * 0.125f);
                float p1 = __expf((sT[kt][r + 1] - mn) * 0.125f);
                sum += p0 + p1;
                float s0 = p0 * 512.0f, s1 = p1 * 512.0f;
                _Float16 h0 = (_Float16)s0, h1 = (_Float16)s1;
                f16x2 hp = {h0, h1};
                f16x2 lp = {(_Float16)(s0 - (float)h0), (_Float16)(s1 - (float)h1)};
                // col = kt*16 + quad*4 + r; chunk = col>>3; within = col&7 (even)
                const int chunk = kt * 2 + (quad >> 1);
                const int within = (quad & 1) * 4 + r;
                const int poff = ln * 32 + ((chunk ^ swz4) << 3) + within;
                *(f16x2*)(&PTh[w][poff]) = hp;
                *(f16x2*)(&PTl[w][poff]) = lp;
            }
        }
        sum += __shfl_xor(sum, 16);
        sum += __shfl_xor(sum, 32);
        l_run = l_run * a + sum;
#pragma unroll
        for (int dt = 0; dt < 4; ++dt) {
            O[dt][0] *= a; O[dt][1] *= a; O[dt][2] *= a; O[dt][3] *= a;
        }
    };

    // ---- prologue: tile0 staged+consumed; tile1 staged; tile2 in regs ----
    LOADT(0);
    STORET(0);
    __syncthreads();                       // tile 0 visible
    LOADT(32);                             // tile 1 -> regs (hides under S/SM)
    {
        f32x4 sT[2];
        STEP_S(0, sT);
        STEP_SM(sT);                       // P(0) -> PT, O *= a0
    }
    STORET(1);                             // tile 1 -> buf1
    __syncthreads();                       // tile 1 visible
    LOADT(64);                             // tile 2 -> regs
    int cur = 1;

    // ---- pipelined main loop: t = 1..63 ----
    for (int k0 = 32; k0 < 2048; k0 += 32) {
        f32x4 sT[2];
        STEP_S(cur, sT);                   // S^T(t)      [MFMA]
        STEP_PV(cur ^ 1);                  // PV(t-1)     [MFMA, independent]
        STEP_SM(sT);                       // softmax(t)  [VALU, overlaps PV]
        __syncthreads();                   // B1: done reading buf[cur^1]
        if (k0 + 32 < 2048) STORET(cur ^ 1);   // tile t+1 -> buf[cur^1]
        __syncthreads();                   // B2: staged writes visible
        if (k0 + 64 < 2048) LOADT(k0 + 64);    // tile t+2 -> regs
        cur ^= 1;
    }
    STEP_PV(cur ^ 1);                      // drain: PV(63)

    // ---- epilogue: O^T[d][q=ln] -> xbuf rows, 4 coalesced float4/lane ----
    const float inv = 1.0f / (512.0f * l_run);
    const long base = ((long)(b * 2048 + q0 + w * 16 + ln)) * 512 + h * 64 + quad * 4;
#pragma unroll
    for (int dt = 0; dt < 4; ++dt) {
        float4 o;
        o.x = O[dt][0] * inv; o.y = O[dt][1] * inv;
        o.z = O[dt][2] * inv; o.w = O[dt][3] * inv;
        *(float4*)(xbuf + base + dt * 16) = o;
    }
}

// ---------------------------------------------------------------------------
// Kernel 5: final GEMM on the f16 MFMA pipe.  UNCHANGED (green R12).
// ---------------------------------------------------------------------------
__global__ __launch_bounds__(256) void final_mfma(
    const _Float16* __restrict__ qX, const _Float16* __restrict__ WhT,
    const _Float16* __restrict__ WlT, const double* __restrict__ sx,
    float* __restrict__ out)
{
    const int m0 = blockIdx.x * 64, n0 = blockIdx.y * 64;
    const int tid = threadIdx.x;
    const int w = tid >> 6, lane = tid & 63;
    const int ln = lane & 15, quad = lane >> 4;

    __shared__ __align__(16) _Float16 As[64 * 72];
    __shared__ __align__(16) _Float16 BhS[64 * 72];
    __shared__ __align__(16) _Float16 BlS[64 * 72];
    const int srow = tid >> 3, scs = (tid & 7) * 8;

    f32x4 c[4];
#pragma unroll
    for (int nt = 0; nt < 4; ++nt) { c[nt][0] = 0; c[nt][1] = 0; c[nt][2] = 0; c[nt][3] = 0; }

    f16x8 a0, a1, h0, h1, l0, l1;
    a0 = *(const f16x8*)(qX + (long)(m0 + srow) * 512 + scs);
    a1 = *(const f16x8*)(qX + (long)(m0 + 32 + srow) * 512 + scs);
    h0 = *(const f16x8*)(WhT + (long)(n0 + srow) * 512 + scs);
    h1 = *(const f16x8*)(WhT + (long)(n0 + 32 + srow) * 512 + scs);
    l0 = *(const f16x8*)(WlT + (long)(n0 + srow) * 512 + scs);
    l1 = *(const f16x8*)(WlT + (long)(n0 + 32 + srow) * 512 + scs);

    for (int k0 = 0; k0 < 512; k0 += 64) {
        __syncthreads();
        *(f16x8*)(As + srow * 72 + scs) = a0;
        *(f16x8*)(As + (32 + srow) * 72 + scs) = a1;
        *(f16x8*)(BhS + srow * 72 + scs) = h0;
        *(f16x8*)(BhS + (32 + srow) * 72 + scs) = h1;
        *(f16x8*)(BlS + srow * 72 + scs) = l0;
        *(f16x8*)(BlS + (32 + srow) * 72 + scs) = l1;
        __syncthreads();
        if (k0 + 64 < 512) {
            a0 = *(const f16x8*)(qX + (long)(m0 + srow) * 512 + k0 + 64 + scs);
            a1 = *(const f16x8*)(qX + (long)(m0 + 32 + srow) * 512 + k0 + 64 + scs);
            h0 = *(const f16x8*)(WhT + (long)(n0 + srow) * 512 + k0 + 64 + scs);
            h1 = *(const f16x8*)(WhT + (long)(n0 + 32 + srow) * 512 + k0 + 64 + scs);
            l0 = *(const f16x8*)(WlT + (long)(n0 + srow) * 512 + k0 + 64 + scs);
            l1 = *(const f16x8*)(WlT + (long)(n0 + 32 + srow) * 512 + k0 + 64 + scs);
        }
#pragma unroll
        for (int ks = 0; ks < 2; ++ks) {
            f16x8 aF = *(const f16x8*)(As + (w * 16 + ln) * 72 + ks * 32 + quad * 8);
#pragma unroll
            for (int nt = 0; nt < 4; ++nt) {
                const int off = (nt * 16 + ln) * 72 + ks * 32 + quad * 8;
                f16x8 bh = *(const f16x8*)(BhS + off);
                f16x8 bl = *(const f16x8*)(BlS + off);
                c[nt] = MFMA16(aF, bl, c[nt]);
                c[nt] = MFMA16(aF, bh, c[nt]);
            }
        }
    }

#pragma unroll
    for (int nt = 0; nt < 4; ++nt)
#pragma unroll
        for (int r = 0; r < 4; ++r) {
            int m = m0 + w * 16 + quad * 4 + r;
            int n = n0 + nt * 16 + ln;
            out[(long)m * 512 + n] = (float)((double)c[nt][r] * sx[m & 2047]);
        }
}

// ---------------------------------------------------------------------------
extern "C" void kernel_launch(void* const* d_in, const int* in_sizes, int n_in,
                              void* d_out, int out_size, void* d_ws, size_t ws_size,
                              hipStream_t stream)
{
    const float* query = (const float*)d_in[0];
    const float* key_  = (const float*)d_in[1];
    const float* value = (const float*)d_in[2];
    const float* Wq = (const float*)d_in[3];
    const float* Wk = (const float*)d_in[4];
    const float* Wv = (const float*)d_in[5];
    const float* Wf = (const float*)d_in[6];
    float* out = (float*)d_out;

    // workspace carve-up: ~70 MB
    char* p = (char*)d_ws;
    auto alloc = [&](size_t bytes) -> char* {
        char* r = p;
        p += (bytes + 255) & ~(size_t)255;
        return r;
    };
    double*   sA   = (double*)alloc(3 * 2048 * 8);
    double*   sx   = (double*)alloc(2048 * 8);
    double*   sw   = (double*)alloc(3 * 512 * 8);
    _Float16* qW   = (_Float16*)alloc((size_t)3 * 512 * 512 * 2);
    const long PE  = (long)8 * 2048 * 64;   // halfs per slot-plane
    _Float16* Qh   = (_Float16*)alloc((size_t)2 * PE * 2);
    _Float16* Ql   = (_Float16*)alloc((size_t)2 * PE * 2);
    _Float16* Kh   = (_Float16*)alloc((size_t)2 * PE * 2);
    _Float16* Kl   = (_Float16*)alloc((size_t)2 * PE * 2);
    _Float16* Vh   = (_Float16*)alloc((size_t)2 * PE * 2);
    _Float16* Vl   = (_Float16*)alloc((size_t)2 * PE * 2);
    float*    xbuf = (float*)alloc((size_t)8192 * 512 * 4);
    _Float16* qA   = (_Float16*)alloc((size_t)3 * 4 * 2048 * 512 * 2);  // also reused as qX
    _Float16* WhT  = (_Float16*)alloc((size_t)512 * 512 * 2);
    _Float16* WlT  = (_Float16*)alloc((size_t)512 * 512 * 2);

    token_scale<<<dim3(2048, 3), 256, 0, stream>>>(query, key_, value, sA);
    wquant<<<dim3(8, 3), 256, 0, stream>>>(Wq, Wk, Wv, sw, qW);
    aquant<<<dim3(2048, 3), 256, 0, stream>>>(query, key_, value, sA, qA);
    wfsplit<<<dim3(8, 8), 256, 0, stream>>>(Wf, WhT, WlT);
    for (int pair = 0; pair < 2; ++pair) {
        proj_mfma<<<dim3(32, 8, 3), 256, 0, stream>>>(qA, qW, sA, sw,
            Qh, Ql, Kh, Kl, Vh, Vl, pair * 2);
        proj_mfma<<<dim3(32, 8, 3), 256, 0, stream>>>(qA, qW, sA, sw,
            Qh + PE, Ql + PE, Kh + PE, Kl + PE, Vh + PE, Vl + PE, pair * 2 + 1);
        attn_mfma<<<dim3(32, 8, 2), 256, 0, stream>>>(Qh, Ql, Kh, Kl, Vh, Vl, xbuf, pair * 2);
    }
    token_scale<<<dim3(2048, 1), 256, 0, stream>>>(xbuf, xbuf, xbuf, sx);
    aquant<<<dim3(2048, 1), 256, 0, stream>>>(xbuf, xbuf, xbuf, sx, qA);  // qX alias
    final_mfma<<<dim3(128, 8), 256, 0, stream>>>(qA, WhT, WlT, sx, out);
}

// Round 9
// 402.213 us; speedup vs baseline: 1.0677x; 1.0677x over previous
//
#include <hip/hip_runtime.h>
#include <math.h>

// ---------------------------------------------------------------------------
// Round 18: single-barrier pipeline + V-in-registers.  R17 (KVBLK=32)
// regressed 87->101: occupancy is GRID-capped (512 blocks / 256 CU = 2
// blocks/CU, LDS irrelevant) and the 64B-row V tile re-introduced 16-bank
// conflicts (1.15e7).  Reverted to green R16.  This round: PV(t-1)'s V
// operands pre-loaded to REGISTERS during iter t-1 (from buf[cur], which no
// one writes that iter) -> iter t reads only buf[cur], writes only
// buf[cur^1] (disjoint) -> ONE barrier per iteration (was 2).  PV becomes a
// pure-register MFMA cluster.  +64 VGPR (~200 total, under 256; occupancy
// grid-capped anyway).  Values/op order bit-identical -> absmax exactly 54.0.
// Predicted: attn 87 -> ~72-78us, MfmaUtil ~28%, total 405 -> ~385us.
// ---------------------------------------------------------------------------

typedef _Float16 f16x8 __attribute__((ext_vector_type(8)));
typedef _Float16 f16x2 __attribute__((ext_vector_type(2)));
typedef float f32x4 __attribute__((ext_vector_type(4)));
#define MFMA16(a, b, c) __builtin_amdgcn_mfma_f32_16x16x32_f16((a), (b), (c), 0, 0, 0)

// ---------------------------------------------------------------------------
// Kernel 1: per-token abs-max scale (f64 decisions).  UNCHANGED (green).
// ---------------------------------------------------------------------------
__global__ __launch_bounds__(256) void token_scale(
    const float* __restrict__ x0, const float* __restrict__ x1,
    const float* __restrict__ x2, double* __restrict__ out)
{
    const int t = blockIdx.x;
    const int z = blockIdx.y;
    const float* __restrict__ x = (z == 0) ? x0 : ((z == 1) ? x1 : x2);
    const int tid = threadIdx.x;
    float m = 0.0f;
#pragma unroll
    for (int i = 0; i < 2; ++i) {
        int f = i * 256 + tid;
        int b = f >> 7, d4 = f & 127;
        float4 v = *(const float4*)(x + (long)(b * 2048 + t) * 512 + d4 * 4);
        m = fmaxf(m, fmaxf(fmaxf(fabsf(v.x), fabsf(v.y)), fmaxf(fabsf(v.z), fabsf(v.w))));
    }
#pragma unroll
    for (int off = 1; off < 64; off <<= 1) m = fmaxf(m, __shfl_xor(m, off));
    __shared__ float red[4];
    if ((tid & 63) == 0) red[tid >> 6] = m;
    __syncthreads();
    if (tid == 0) {
        m = fmaxf(fmaxf(red[0], red[1]), fmaxf(red[2], red[3]));
        out[z * 2048 + t] = fmax((double)m / 127.0, 1e-8);
    }
}

// ---------------------------------------------------------------------------
// Kernel 2: weight quantization.  UNCHANGED (green R11).
// ---------------------------------------------------------------------------
__global__ __launch_bounds__(256) void wquant(
    const float* __restrict__ Wq, const float* __restrict__ Wk,
    const float* __restrict__ Wv, double* __restrict__ sw,
    _Float16* __restrict__ qW)
{
    const int z = blockIdx.y;
    const float* __restrict__ W = (z == 0) ? Wq : (z == 1) ? Wk : Wv;
    const int col0 = blockIdx.x * 64;
    const int tid = threadIdx.x;
    const int c = tid & 63, kg = tid >> 6;

    __shared__ float redm[4][64];
    __shared__ double sS[64];
    __shared__ __align__(16) _Float16 qs[64][520];

    float m = 0.0f;
    for (int k = kg; k < 512; k += 4)
        m = fmaxf(m, fabsf(W[k * 512 + col0 + c]));
    redm[kg][c] = m;
    __syncthreads();
    if (tid < 64) {
        float mm = fmaxf(fmaxf(redm[0][tid], redm[1][tid]),
                         fmaxf(redm[2][tid], redm[3][tid]));
        double s = fmax((double)mm / 127.0, 1e-8);
        sw[z * 512 + col0 + tid] = s;
        sS[tid] = s;
    }
    __syncthreads();

    const double s = sS[c];
    for (int k = kg; k < 512; k += 4)
        qs[c][k] = (_Float16)fmin(fmax(rint((double)W[k * 512 + col0 + c] / s), -128.0), 127.0);
    __syncthreads();

    const int wc = tid >> 2, kc = (tid & 3) * 128;
    _Float16* q = qW + (long)z * 262144 + (long)(col0 + wc) * 512 + kc;
#pragma unroll
    for (int j = 0; j < 16; ++j)
        *(f16x8*)(q + j * 8) = *(const f16x8*)(&qs[wc][kc + j * 8]);
}

// ---------------------------------------------------------------------------
// Kernel 2b: activation quantization into f16 int planes.  UNCHANGED (R12).
// ---------------------------------------------------------------------------
__global__ __launch_bounds__(256) void aquant(
    const float* __restrict__ x0, const float* __restrict__ x1,
    const float* __restrict__ x2, const double* __restrict__ sAll,
    _Float16* __restrict__ qA)
{
    const int z = blockIdx.y;
    const float* __restrict__ x = (z == 0) ? x0 : ((z == 1) ? x1 : x2);
    const double* __restrict__ s = sAll + z * 2048;
    const long PLANE = (long)4 * 2048 * 512;
    const long f = ((long)blockIdx.x * 256 + threadIdx.x) * 8;
    float4 v0 = *(const float4*)(x + f);
    float4 v1 = *(const float4*)(x + f + 4);
    const double sc = s[(f >> 9) & 2047];
    f16x8 q;
    q[0] = (_Float16)fmin(fmax(rint((double)v0.x / sc), -128.0), 127.0);
    q[1] = (_Float16)fmin(fmax(rint((double)v0.y / sc), -128.0), 127.0);
    q[2] = (_Float16)fmin(fmax(rint((double)v0.z / sc), -128.0), 127.0);
    q[3] = (_Float16)fmin(fmax(rint((double)v0.w / sc), -128.0), 127.0);
    q[4] = (_Float16)fmin(fmax(rint((double)v1.x / sc), -128.0), 127.0);
    q[5] = (_Float16)fmin(fmax(rint((double)v1.y / sc), -128.0), 127.0);
    q[6] = (_Float16)fmin(fmax(rint((double)v1.z / sc), -128.0), 127.0);
    q[7] = (_Float16)fmin(fmax(rint((double)v1.w / sc), -128.0), 127.0);
    *(f16x8*)(qA + (long)z * PLANE + f) = q;
}

// ---------------------------------------------------------------------------
// Kernel 2c: one-shot Wf transpose + Dekker hi/lo split.  UNCHANGED (R12).
// ---------------------------------------------------------------------------
__global__ __launch_bounds__(256) void wfsplit(
    const float* __restrict__ Wf, _Float16* __restrict__ WhT,
    _Float16* __restrict__ WlT)
{
    const int n0 = blockIdx.x * 64, k0 = blockIdx.y * 64;
    const int tid = threadIdx.x;
    __shared__ float T[64 * 68];
    {
        const int kr = tid >> 2, nc = (tid & 3) * 16;
#pragma unroll
        for (int j = 0; j < 4; ++j) {
            float4 v = *(const float4*)(Wf + (long)(k0 + kr) * 512 + n0 + nc + 4 * j);
            T[kr * 68 + nc + 4 * j + 0] = v.x;
            T[kr * 68 + nc + 4 * j + 1] = v.y;
            T[kr * 68 + nc + 4 * j + 2] = v.z;
            T[kr * 68 + nc + 4 * j + 3] = v.w;
        }
    }
    __syncthreads();
    const int nr = tid >> 2, kc = (tid & 3) * 16;
    f16x8 h[2], l[2];
#pragma unroll
    for (int j = 0; j < 16; ++j) {
        float wv = T[(kc + j) * 68 + nr];
        _Float16 hi = (_Float16)wv;
        h[j >> 3][j & 7] = hi;
        l[j >> 3][j & 7] = (_Float16)(wv - (float)hi);
    }
    *(f16x8*)(WhT + (long)(n0 + nr) * 512 + k0 + kc) = h[0];
    *(f16x8*)(WhT + (long)(n0 + nr) * 512 + k0 + kc + 8) = h[1];
    *(f16x8*)(WlT + (long)(n0 + nr) * 512 + k0 + kc) = l[0];
    *(f16x8*)(WlT + (long)(n0 + nr) * 512 + k0 + kc + 8) = l[1];
}

// ---------------------------------------------------------------------------
// Kernel 3: projection GEMM on the f16 MFMA pipe.  UNCHANGED (green R12).
// ---------------------------------------------------------------------------
__global__ __launch_bounds__(256) void proj_mfma(
    const _Float16* __restrict__ qA, const _Float16* __restrict__ qW,
    const double* __restrict__ saAll, const double* __restrict__ swAll,
    _Float16* __restrict__ Qh, _Float16* __restrict__ Ql,
    _Float16* __restrict__ Kh, _Float16* __restrict__ Kl,
    _Float16* __restrict__ Vh, _Float16* __restrict__ Vl,
    int b)
{
    const int z = blockIdx.z;
    const _Float16* __restrict__ A = qA + ((long)z * 4 + b) * (2048l * 512);
    const _Float16* __restrict__ Bq = qW + (long)z * 262144;
    const double* __restrict__ sa = saAll + z * 2048;
    const double* __restrict__ swz = swAll + z * 512;

    const int m0 = blockIdx.x * 64, n0 = blockIdx.y * 64;
    const int tid = threadIdx.x;
    const int w = tid >> 6, lane = tid & 63;
    const int ln = lane & 15, quad = lane >> 4;

    __shared__ __align__(16) _Float16 As[64 * 72];
    __shared__ __align__(16) _Float16 Bs[64 * 72];
    const int srow = tid >> 3, scs = (tid & 7) * 8;

    f32x4 c[4];
#pragma unroll
    for (int nt = 0; nt < 4; ++nt) { c[nt][0] = 0; c[nt][1] = 0; c[nt][2] = 0; c[nt][3] = 0; }

    f16x8 a0, a1, b0, b1;
    a0 = *(const f16x8*)(A + (long)(m0 + srow) * 512 + scs);
    a1 = *(const f16x8*)(A + (long)(m0 + 32 + srow) * 512 + scs);
    b0 = *(const f16x8*)(Bq + (long)(n0 + srow) * 512 + scs);
    b1 = *(const f16x8*)(Bq + (long)(n0 + 32 + srow) * 512 + scs);

    for (int k0 = 0; k0 < 512; k0 += 64) {
        __syncthreads();
        *(f16x8*)(As + srow * 72 + scs) = a0;
        *(f16x8*)(As + (32 + srow) * 72 + scs) = a1;
        *(f16x8*)(Bs + srow * 72 + scs) = b0;
        *(f16x8*)(Bs + (32 + srow) * 72 + scs) = b1;
        __syncthreads();
        if (k0 + 64 < 512) {
            a0 = *(const f16x8*)(A + (long)(m0 + srow) * 512 + k0 + 64 + scs);
            a1 = *(const f16x8*)(A + (long)(m0 + 32 + srow) * 512 + k0 + 64 + scs);
            b0 = *(const f16x8*)(Bq + (long)(n0 + srow) * 512 + k0 + 64 + scs);
            b1 = *(const f16x8*)(Bq + (long)(n0 + 32 + srow) * 512 + k0 + 64 + scs);
        }
#pragma unroll
        for (int ks = 0; ks < 2; ++ks) {
            f16x8 aF = *(const f16x8*)(As + (w * 16 + ln) * 72 + ks * 32 + quad * 8);
#pragma unroll
            for (int nt = 0; nt < 4; ++nt) {
                f16x8 bF = *(const f16x8*)(Bs + (nt * 16 + ln) * 72 + ks * 32 + quad * 8);
                c[nt] = MFMA16(aF, bF, c[nt]);
            }
        }
    }

#pragma unroll
    for (int nt = 0; nt < 4; ++nt)
#pragma unroll
        for (int r = 0; r < 4; ++r) {
            int t = m0 + w * 16 + quad * 4 + r;
            int n = n0 + nt * 16 + ln;
            float val = (float)((double)c[nt][r] * sa[t] * swz[n]);
            _Float16 hi = (_Float16)val;
            _Float16 lo = (_Float16)(val - (float)hi);
            int hh = n >> 6, d = n & 63;
            if (z == 2) {
                long idx = ((long)hh * 64 + d) * 2048 + t;     // transposed
                Vh[idx] = hi; Vl[idx] = lo;
            } else if (z == 1) {
                long idx = ((long)hh * 2048 + t) * 64 + d;
                Kh[idx] = hi; Kl[idx] = lo;
            } else {
                long idx = ((long)hh * 2048 + t) * 64 + d;
                Qh[idx] = hi; Ql[idx] = lo;
            }
        }
}

// ---------------------------------------------------------------------------
// Kernel 4: attention — R16 skeleton + V-in-registers + 1 barrier/iter.
// 4 waves / 64 q, KVBLK=64, double-buffered swizzled LDS (80 KB).
// ---------------------------------------------------------------------------
__global__ __launch_bounds__(256) void attn_mfma(
    const _Float16* __restrict__ Qh0, const _Float16* __restrict__ Ql0,
    const _Float16* __restrict__ Kh0, const _Float16* __restrict__ Kl0,
    const _Float16* __restrict__ Vh0, const _Float16* __restrict__ Vl0,
    float* __restrict__ xbuf, int bbase)
{
    // ---- XCD-aware bijective remap (R14): XCD x owns head x, both slots ----
    const int wg = blockIdx.x + (blockIdx.y << 5) + (blockIdx.z << 8);
    const int xcd = wg & 7, j = wg >> 3;
    const int pair = (xcd << 1) + (j >> 5);
    const int q0 = (j & 31) * 64;
    const int h = pair >> 1;
    const int slot = pair & 1;
    const int b = bbase + slot;

    const long PE = (long)8 * 2048 * 64;
    const _Float16* __restrict__ Qh = Qh0 + (long)slot * PE;
    const _Float16* __restrict__ Ql = Ql0 + (long)slot * PE;
    const _Float16* __restrict__ Kh = Kh0 + (long)slot * PE;
    const _Float16* __restrict__ Kl = Kl0 + (long)slot * PE;
    const _Float16* __restrict__ Vh = Vh0 + (long)slot * PE;
    const _Float16* __restrict__ Vl = Vl0 + (long)slot * PE;

    const int tid = threadIdx.x;
    const int w = tid >> 6, lane = tid & 63;
    const int ln = lane & 15, quad = lane >> 4;
    const int swz = ln & 7;

    // double-buffered swizzled K/V tiles + wave-private P^T: 80 KB total
    __shared__ __align__(16) _Float16 KsH[2][4096];
    __shared__ __align__(16) _Float16 KsL[2][4096];
    __shared__ __align__(16) _Float16 VsH[2][4096];
    __shared__ __align__(16) _Float16 VsL[2][4096];
    __shared__ __align__(16) _Float16 PTh[4][1024];
    __shared__ __align__(16) _Float16 PTl[4][1024];

    // Q fragment registers (same content serves as Q^T B-operand)
    f16x8 qh[2], ql[2];
    {
        const long r = ((long)h * 2048 + q0 + w * 16 + ln) * 64 + quad * 8;
        qh[0] = *(const f16x8*)(Qh + r);
        qh[1] = *(const f16x8*)(Qh + r + 32);
        ql[0] = *(const f16x8*)(Ql + r);
        ql[1] = *(const f16x8*)(Ql + r + 32);
    }

    float m_run = -INFINITY, l_run = 0.0f;
    f32x4 O[4];
#pragma unroll
    for (int dt = 0; dt < 4; ++dt) { O[dt][0] = 0; O[dt][1] = 0; O[dt][2] = 0; O[dt][3] = 0; }

    // V fragments of tile t held in REGISTERS (consumed by PV at iter t+1)
    f16x8 vrh[8], vrl[8];   // [ks2*4 + dt]

    const int srow = tid >> 3, scs = (tid & 7) * 8;
    const int tsl = (((tid & 7) ^ (srow & 7)) << 3);
    const long kBase = (long)h * 2048;
    const long vBase = (long)h * 64;
    f16x8 sg0, sg1, sg2, sg3, sg4, sg5, sg6, sg7;

    auto LOADT = [&](int kt) {
        sg0 = *(const f16x8*)(Kh + (kBase + kt + srow) * 64 + scs);
        sg1 = *(const f16x8*)(Kh + (kBase + kt + 32 + srow) * 64 + scs);
        sg2 = *(const f16x8*)(Kl + (kBase + kt + srow) * 64 + scs);
        sg3 = *(const f16x8*)(Kl + (kBase + kt + 32 + srow) * 64 + scs);
        sg4 = *(const f16x8*)(Vh + (vBase + srow) * 2048 + kt + scs);
        sg5 = *(const f16x8*)(Vh + (vBase + 32 + srow) * 2048 + kt + scs);
        sg6 = *(const f16x8*)(Vl + (vBase + srow) * 2048 + kt + scs);
        sg7 = *(const f16x8*)(Vl + (vBase + 32 + srow) * 2048 + kt + scs);
    };
    auto STORET = [&](int bs) {
        const int li  = srow * 64 + tsl;
        const int li2 = (32 + srow) * 64 + tsl;
        *(f16x8*)(&KsH[bs][li])  = sg0;  *(f16x8*)(&KsH[bs][li2]) = sg1;
        *(f16x8*)(&KsL[bs][li])  = sg2;  *(f16x8*)(&KsL[bs][li2]) = sg3;
        *(f16x8*)(&VsH[bs][li])  = sg4;  *(f16x8*)(&VsH[bs][li2]) = sg5;
        *(f16x8*)(&VsL[bs][li])  = sg6;  *(f16x8*)(&VsL[bs][li2]) = sg7;
    };
    auto STEP_S = [&](int bs, f32x4* sT) {
        __builtin_amdgcn_s_setprio(1);
#pragma unroll
        for (int kt = 0; kt < 4; ++kt) {
            f32x4 s; s[0] = 0; s[1] = 0; s[2] = 0; s[3] = 0;
#pragma unroll
            for (int ks = 0; ks < 2; ++ks) {
                const int off = (kt * 16 + ln) * 64 + (((ks * 4 + quad) ^ swz) << 3);
                f16x8 kh = *(const f16x8*)(&KsH[bs][off]);
                f16x8 kl = *(const f16x8*)(&KsL[bs][off]);
                s = MFMA16(kl, qh[ks], s);
                s = MFMA16(kh, ql[ks], s);
                s = MFMA16(kh, qh[ks], s);
            }
            sT[kt] = s;
        }
        __builtin_amdgcn_s_setprio(0);
    };
    auto VLOAD = [&](int bs) {   // V(t) frags buf[bs] -> registers
#pragma unroll
        for (int ks2 = 0; ks2 < 2; ++ks2) {
            const int psl = (((ks2 * 4 + quad) ^ swz) << 3);
#pragma unroll
            for (int dt = 0; dt < 4; ++dt) {
                const int off = (dt * 16 + ln) * 64 + psl;
                vrh[ks2 * 4 + dt] = *(const f16x8*)(&VsH[bs][off]);
                vrl[ks2 * 4 + dt] = *(const f16x8*)(&VsL[bs][off]);
            }
        }
    };
    auto STEP_PV = [&]() {       // PV(t-1): pure-register MFMA cluster
        __builtin_amdgcn_s_setprio(1);
#pragma unroll
        for (int ks2 = 0; ks2 < 2; ++ks2) {
            const int psl = (((ks2 * 4 + quad) ^ swz) << 3);
            f16x8 ph = *(const f16x8*)(&PTh[w][ln * 64 + psl]);
            f16x8 pl = *(const f16x8*)(&PTl[w][ln * 64 + psl]);
#pragma unroll
            for (int dt = 0; dt < 4; ++dt) {
                O[dt] = MFMA16(vrh[ks2 * 4 + dt], pl, O[dt]);
                O[dt] = MFMA16(vrl[ks2 * 4 + dt], ph, O[dt]);
                O[dt] = MFMA16(vrh[ks2 * 4 + dt], ph, O[dt]);
            }
        }
        __builtin_amdgcn_s_setprio(0);
    };
    auto STEP_SM = [&](f32x4* sT) {
        float rm = -INFINITY;
#pragma unroll
        for (int kt = 0; kt < 4; ++kt)
#pragma unroll
            for (int r = 0; r < 4; ++r) rm = fmaxf(rm, sT[kt][r]);
        rm = fmaxf(rm, __shfl_xor(rm, 16));
        rm = fmaxf(rm, __shfl_xor(rm, 32));
        const float mn = fmaxf(m_run, rm);
        const float a = __expf((m_run - mn) * 0.125f);
        m_run = mn;
        float sum = 0.0f;
#pragma unroll
        for (int kt = 0; kt < 4; ++kt) {
#pragma unroll
            for (int r = 0; r < 4; r += 2) {
                float p0 = __expf((sT[kt][r]     - mn) * 0.125f);
                float p1 = __expf((sT[kt][r + 1] - mn) * 0.125f);
                sum += p0 + p1;
                float s0 = p0 * 512.0f, s1 = p1 * 512.0f;
                _Float16 h0 = (_Float16)s0, h1 = (_Float16)s1;
                f16x2 hp = {h0, h1};
                f16x2 lp = {(_Float16)(s0 - (float)h0), (_Float16)(s1 - (float)h1)};
                const int cb = (kt * 32 + quad * 8 + 2 * r) ^ (swz << 4);
                const int poff = ln * 64 + (cb >> 1);
                *(f16x2*)(&PTh[w][poff]) = hp;
                *(f16x2*)(&PTl[w][poff]) = lp;
            }
        }
        sum += __shfl_xor(sum, 16);
        sum += __shfl_xor(sum, 32);
        l_run = l_run * a + sum;
#pragma unroll
        for (int dt = 0; dt < 4; ++dt) {
            O[dt][0] *= a; O[dt][1] *= a; O[dt][2] *= a; O[dt][3] *= a;
        }
    };

    // ---- prologue: tile0 staged+consumed (V0 -> regs); tile1 staged ----
    LOADT(0);
    STORET(0);
    __syncthreads();                       // tile 0 visible
    LOADT(64);                             // tile 1 -> sg regs
    {
        f32x4 sT[4];
        STEP_S(0, sT);
        VLOAD(0);                          // V(0) -> registers
        STEP_SM(sT);                       // P(0) -> PT, O *= a0
    }
    STORET(1);                             // tile 1 -> buf1
    LOADT(128);                            // tile 2 -> sg regs
    __syncthreads();                       // tile 1 visible (single barrier)
    int cur = 1;

    // ---- pipelined main loop, ONE barrier per iteration ----
    for (int k0 = 64; k0 < 2048; k0 += 64) {
        f32x4 sT[4];
        STEP_S(cur, sT);                   // S^T(t)     [MFMA, reads buf[cur]]
        STEP_PV();                         // PV(t-1)    [MFMA, registers + wave-private PT]
        VLOAD(cur);                        // V(t) -> regs [reads buf[cur]]
        STEP_SM(sT);                       // softmax(t) [VALU] ; P(t)->PT ; O*=a
        if (k0 + 64 < 2048) STORET(cur ^ 1);   // tile t+1 -> buf[cur^1] (disjoint)
        if (k0 + 128 < 2048) LOADT(k0 + 128);  // tile t+2 -> sg regs
        __syncthreads();                   // writes visible; next iter reads buf[cur^1]
        cur ^= 1;
    }
    STEP_PV();                             // drain: PV(31)

    // ---- epilogue: O^T[d][q=ln] -> xbuf rows, 4 coalesced float4/lane ----
    const float inv = 1.0f / (512.0f * l_run);
    const long base = ((long)(b * 2048 + q0 + w * 16 + ln)) * 512 + h * 64 + quad * 4;
#pragma unroll
    for (int dt = 0; dt < 4; ++dt) {
        float4 o;
        o.x = O[dt][0] * inv; o.y = O[dt][1] * inv;
        o.z = O[dt][2] * inv; o.w = O[dt][3] * inv;
        *(float4*)(xbuf + base + dt * 16) = o;
    }
}

// ---------------------------------------------------------------------------
// Kernel 5: final GEMM on the f16 MFMA pipe.  UNCHANGED (green R12).
// ---------------------------------------------------------------------------
__global__ __launch_bounds__(256) void final_mfma(
    const _Float16* __restrict__ qX, const _Float16* __restrict__ WhT,
    const _Float16* __restrict__ WlT, const double* __restrict__ sx,
    float* __restrict__ out)
{
    const int m0 = blockIdx.x * 64, n0 = blockIdx.y * 64;
    const int tid = threadIdx.x;
    const int w = tid >> 6, lane = tid & 63;
    const int ln = lane & 15, quad = lane >> 4;

    __shared__ __align__(16) _Float16 As[64 * 72];
    __shared__ __align__(16) _Float16 BhS[64 * 72];
    __shared__ __align__(16) _Float16 BlS[64 * 72];
    const int srow = tid >> 3, scs = (tid & 7) * 8;

    f32x4 c[4];
#pragma unroll
    for (int nt = 0; nt < 4; ++nt) { c[nt][0] = 0; c[nt][1] = 0; c[nt][2] = 0; c[nt][3] = 0; }

    f16x8 a0, a1, h0, h1, l0, l1;
    a0 = *(const f16x8*)(qX + (long)(m0 + srow) * 512 + scs);
    a1 = *(const f16x8*)(qX + (long)(m0 + 32 + srow) * 512 + scs);
    h0 = *(const f16x8*)(WhT + (long)(n0 + srow) * 512 + scs);
    h1 = *(const f16x8*)(WhT + (long)(n0 + 32 + srow) * 512 + scs);
    l0 = *(const f16x8*)(WlT + (long)(n0 + srow) * 512 + scs);
    l1 = *(const f16x8*)(WlT + (long)(n0 + 32 + srow) * 512 + scs);

    for (int k0 = 0; k0 < 512; k0 += 64) {
        __syncthreads();
        *(f16x8*)(As + srow * 72 + scs) = a0;
        *(f16x8*)(As + (32 + srow) * 72 + scs) = a1;
        *(f16x8*)(BhS + srow * 72 + scs) = h0;
        *(f16x8*)(BhS + (32 + srow) * 72 + scs) = h1;
        *(f16x8*)(BlS + srow * 72 + scs) = l0;
        *(f16x8*)(BlS + (32 + srow) * 72 + scs) = l1;
        __syncthreads();
        if (k0 + 64 < 512) {
            a0 = *(const f16x8*)(qX + (long)(m0 + srow) * 512 + k0 + 64 + scs);
            a1 = *(const f16x8*)(qX + (long)(m0 + 32 + srow) * 512 + k0 + 64 + scs);
            h0 = *(const f16x8*)(WhT + (long)(n0 + srow) * 512 + k0 + 64 + scs);
            h1 = *(const f16x8*)(WhT + (long)(n0 + 32 + srow) * 512 + k0 + 64 + scs);
            l0 = *(const f16x8*)(WlT + (long)(n0 + srow) * 512 + k0 + 64 + scs);
            l1 = *(const f16x8*)(WlT + (long)(n0 + 32 + srow) * 512 + k0 + 64 + scs);
        }
#pragma unroll
        for (int ks = 0; ks < 2; ++ks) {
            f16x8 aF = *(const f16x8*)(As + (w * 16 + ln) * 72 + ks * 32 + quad * 8);
#pragma unroll
            for (int nt = 0; nt < 4; ++nt) {
                const int off = (nt * 16 + ln) * 72 + ks * 32 + quad * 8;
                f16x8 bh = *(const f16x8*)(BhS + off);
                f16x8 bl = *(const f16x8*)(BlS + off);
                c[nt] = MFMA16(aF, bl, c[nt]);
                c[nt] = MFMA16(aF, bh, c[nt]);
            }
        }
    }

#pragma unroll
    for (int nt = 0; nt < 4; ++nt)
#pragma unroll
        for (int r = 0; r < 4; ++r) {
            int m = m0 + w * 16 + quad * 4 + r;
            int n = n0 + nt * 16 + ln;
            out[(long)m * 512 + n] = (float)((double)c[nt][r] * sx[m & 2047]);
        }
}

// ---------------------------------------------------------------------------
extern "C" void kernel_launch(void* const* d_in, const int* in_sizes, int n_in,
                              void* d_out, int out_size, void* d_ws, size_t ws_size,
                              hipStream_t stream)
{
    const float* query = (const float*)d_in[0];
    const float* key_  = (const float*)d_in[1];
    const float* value = (const float*)d_in[2];
    const float* Wq = (const float*)d_in[3];
    const float* Wk = (const float*)d_in[4];
    const float* Wv = (const float*)d_in[5];
    const float* Wf = (const float*)d_in[6];
    float* out = (float*)d_out;

    // workspace carve-up: ~70 MB
    char* p = (char*)d_ws;
    auto alloc = [&](size_t bytes) -> char* {
        char* r = p;
        p += (bytes + 255) & ~(size_t)255;
        return r;
    };
    double*   sA   = (double*)alloc(3 * 2048 * 8);
    double*   sx   = (double*)alloc(2048 * 8);
    double*   sw   = (double*)alloc(3 * 512 * 8);
    _Float16* qW   = (_Float16*)alloc((size_t)3 * 512 * 512 * 2);
    const long PE  = (long)8 * 2048 * 64;   // halfs per slot-plane
    _Float16* Qh   = (_Float16*)alloc((size_t)2 * PE * 2);
    _Float16* Ql   = (_Float16*)alloc((size_t)2 * PE * 2);
    _Float16* Kh   = (_Float16*)alloc((size_t)2 * PE * 2);
    _Float16* Kl   = (_Float16*)alloc((size_t)2 * PE * 2);
    _Float16* Vh   = (_Float16*)alloc((size_t)2 * PE * 2);
    _Float16* Vl   = (_Float16*)alloc((size_t)2 * PE * 2);
    float*    xbuf = (float*)alloc((size_t)8192 * 512 * 4);
    _Float16* qA   = (_Float16*)alloc((size_t)3 * 4 * 2048 * 512 * 2);  // also reused as qX
    _Float16* WhT  = (_Float16*)alloc((size_t)512 * 512 * 2);
    _Float16* WlT  = (_Float16*)alloc((size_t)512 * 512 * 2);

    token_scale<<<dim3(2048, 3), 256, 0, stream>>>(query, key_, value, sA);
    wquant<<<dim3(8, 3), 256, 0, stream>>>(Wq, Wk, Wv, sw, qW);
    aquant<<<dim3(2048, 3), 256, 0, stream>>>(query, key_, value, sA, qA);
    wfsplit<<<dim3(8, 8), 256, 0, stream>>>(Wf, WhT, WlT);
    for (int pair = 0; pair < 2; ++pair) {
        proj_mfma<<<dim3(32, 8, 3), 256, 0, stream>>>(qA, qW, sA, sw,
            Qh, Ql, Kh, Kl, Vh, Vl, pair * 2);
        proj_mfma<<<dim3(32, 8, 3), 256, 0, stream>>>(qA, qW, sA, sw,
            Qh + PE, Ql + PE, Kh + PE, Kl + PE, Vh + PE, Vl + PE, pair * 2 + 1);
        attn_mfma<<<dim3(32, 8, 2), 256, 0, stream>>>(Qh, Ql, Kh, Kl, Vh, Vl, xbuf, pair * 2);
    }
    token_scale<<<dim3(2048, 1), 256, 0, stream>>>(xbuf, xbuf, xbuf, sx);
    aquant<<<dim3(2048, 1), 256, 0, stream>>>(xbuf, xbuf, xbuf, sx, qA);  // qX alias
    final_mfma<<<dim3(128, 8), 256, 0, stream>>>(qA, WhT, WlT, sx, out);
}